// Round 2
// baseline (417.200 us; speedup 1.0000x reference)
//
#include <hip/hip_runtime.h>

#define L_DIM 256
#define M_DIM 512
#define Q_DIM 21
#define QQ    441   // 21*21
#define QPAD  22    // padded LDS row stride (floats): 88B rows -> <=2-way bank alias on b64

// ---------------- prep: one-hot -> premultiplied byte-offset index table ----------------
// Xt[j*M + m] = argmax_b X_oh[m,j,b] * (QPAD*4)   (u16 byte offset into LDS J-block)
__global__ __launch_bounds__(256) void ardca_prep(const float* __restrict__ X_oh,
                                                  unsigned short* __restrict__ Xt) {
  int idx = blockIdx.x * 256 + threadIdx.x;          // 512*256 = 131072 = M*L
  int m = idx >> 8;                                  // L = 256
  int j = idx & 255;
  const float* p = X_oh + (size_t)idx * Q_DIM;       // (m*L + j)*Q
  int x = 0;
#pragma unroll
  for (int a = 0; a < Q_DIM; ++a) x = (p[a] > 0.5f) ? a : x;
  Xt[j * M_DIM + m] = (unsigned short)(x * (QPAD * 4));
}

// stage one contiguous 441-float J block into LDS with row stride QPAD
__device__ __forceinline__ void stage_block(float* __restrict__ dst,
                                            const float* __restrict__ src, int t) {
#pragma unroll
  for (int r = 0; r < 2; ++r) {
    int e = t + r * 256;
    if (e < QQ) {
      int x = (e * 3121) >> 16;        // floor(e/21), exact for e < 441
      int a = e - x * Q_DIM;
      dst[x * QPAD + a] = src[e];
    }
  }
}

// ---------------- main: out[m,i,a] = h[i,a] + sum_{j<i} J[i,j,x_mj,a] ----------------
// USE_XT=1: indices from the u16 table in d_ws. USE_XT=0: inline argmax fallback.
template <int USE_XT>
__global__ __launch_bounds__(256) void ardca_main(const float* __restrict__ Jm,
                                                  const float* __restrict__ h,
                                                  const unsigned short* __restrict__ Xt,
                                                  const float* __restrict__ X_oh,
                                                  float* __restrict__ out) {
  __shared__ float lds[2][Q_DIM * QPAD];             // 2 x 462 floats = 3.7 KB
  int b = blockIdx.x;
  int i, mbase;
  if (b < 256) { i = b;        mbase = 0;   }        // block c     -> i = c,      m in [0,256)
  else         { i = 511 - b;  mbase = 256; }        // block c+256 -> i = 255-c,  m in [256,512)
  int t = threadIdx.x;
  int m = mbase + t;

  float acc[QPAD];
#pragma unroll
  for (int a = 0; a < QPAD; ++a) acc[a] = 0.0f;

  const float* Jrow = Jm + (size_t)i * (L_DIM * QQ); // row-i panel, blocks contiguous in j
  const unsigned short* xrow = Xt + m;

  if (i > 0) {
    stage_block(lds[0], Jrow, t);
    __syncthreads();
  }
  for (int j = 0; j < i; ++j) {
    int cur = j & 1;
    if (j + 1 < i) stage_block(lds[cur ^ 1], Jrow + (size_t)(j + 1) * QQ, t);
    unsigned int off;
    if (USE_XT) {
      off = xrow[(size_t)j * M_DIM];                 // x*88, 8B-aligned
    } else {
      const float* p = X_oh + ((size_t)m * L_DIM + j) * Q_DIM;
      int x = 0;
#pragma unroll
      for (int a = 0; a < Q_DIM; ++a) x = (p[a] > 0.5f) ? a : x;
      off = (unsigned int)(x * (QPAD * 4));
    }
    const float* row = (const float*)((const char*)lds[cur] + off);
#pragma unroll
    for (int k = 0; k < QPAD / 2; ++k) {             // 11x ds_read_b64
      float2 v = *(const float2*)(row + 2 * k);
      acc[2 * k]     += v.x;
      acc[2 * k + 1] += v.y;
    }
    __syncthreads();
  }

  const float* hp = h + i * Q_DIM;
  float* o = out + ((size_t)m * L_DIM + i) * Q_DIM;
#pragma unroll
  for (int a = 0; a < Q_DIM; ++a) o[a] = acc[a] + hp[a];
}

extern "C" void kernel_launch(void* const* d_in, const int* in_sizes, int n_in,
                              void* d_out, int out_size, void* d_ws, size_t ws_size,
                              hipStream_t stream) {
  const float* X_oh = (const float*)d_in[0];
  const float* h    = (const float*)d_in[1];
  const float* Jm   = (const float*)d_in[2];
  float* out        = (float*)d_out;
  unsigned short* Xt = (unsigned short*)d_ws;        // needs 131072 * 2B = 256 KB

  if (ws_size >= (size_t)M_DIM * L_DIM * sizeof(unsigned short)) {
    ardca_prep<<<512, 256, 0, stream>>>(X_oh, Xt);
    ardca_main<1><<<512, 256, 0, stream>>>(Jm, h, Xt, X_oh, out);
  } else {
    ardca_main<0><<<512, 256, 0, stream>>>(Jm, h, Xt, X_oh, out);
  }
}

// Round 4
// 218.850 us; speedup vs baseline: 1.9063x; 1.9063x over previous
//
#include <hip/hip_runtime.h>

#define L_DIM 256
#define M_DIM 512
#define Q_DIM 21
#define QQ    441
#define BLKB  1764          // bytes per 21x21 J block
#define BUFS  2304          // LDS buffer stride: 2048B J window + 256B idx
#define NBUF  8
#define DEPTH 6             // stage col j+DEPTH at iter j; wait vmcnt(3*DEPTH)

#define GLD(src, dst, sz) __builtin_amdgcn_global_load_lds( \
    (const __attribute__((address_space(1))) void*)(src),   \
    (__attribute__((address_space(3))) void*)(dst), sz, 0, 0)

// ---- prep: one-hot -> u16 byte-offset table  Xt[j*512 + m] = 84 * argmax ----
// wave-cooperative: 63 consecutive floats per load = 3 one-hot rows; ballot+ctz.
__global__ __launch_bounds__(64) void ardca_prep(const float* __restrict__ X_oh,
                                                 unsigned short* __restrict__ Xt) {
  int w = blockIdx.x;                       // 2048 waves, 64 rows each
  int lane = threadIdx.x;
  const float* base = X_oh + (size_t)w * (64 * Q_DIM);   // 1344 floats
  int rowbase = w * 64;                     // global row id = m*256 + j
#pragma unroll 1
  for (int p = 0; p < 22; ++p) {
    int f = p * 63 + lane;
    float v = (lane < 63 && f < 1344) ? base[f] : 0.0f;
    unsigned long long mask = __ballot(v > 0.5f);
    if (lane < 3) {
      int rloc = 3 * p + lane;
      if (rloc < 64) {
        unsigned int bits = (unsigned int)((mask >> (21 * lane)) & 0x1FFFFFu);
        int x = bits ? __builtin_ctz(bits) : 0;
        int rr = rowbase + rloc;
        int m = rr >> 8, j = rr & 255;
        Xt[j * M_DIM + m] = (unsigned short)(x * 84);
      }
    }
  }
}

// ---- main: out[m,i,a] = h[i,a] + sum_{j<i} J[i,j,x_mj,a] ----
// 1 wave per block; barrier-free; counted-vmcnt pipelined global_load_lds.
template <int USE_XT>
__global__ __launch_bounds__(64) void ardca_main(const float* __restrict__ Jm,
                                                 const float* __restrict__ h,
                                                 const unsigned short* __restrict__ Xt,
                                                 const float* __restrict__ X_oh,
                                                 float* __restrict__ out) {
  alignas(16) __shared__ char lds[NBUF * BUFS];   // 18432 B -> 8 blocks/CU
  int b = blockIdx.x;
  int c = b & 7;                 // XCD (dispatch round-robin)
  int r = b >> 3;
  int mg = r & 7;                // m-group of 64
  int i = ((31 - (r >> 3)) << 3) | c;   // i == c (mod 8): panel stays in one XCD L2
  int lane = threadIdx.x;
  int m = mg * 64 + lane;

  const char* Jrow = (const char*)Jm + (size_t)i * (256ull * BLKB); // 16B-aligned
  const char* XtB  = (const char*)Xt;

  float acc[Q_DIM];
#pragma unroll
  for (int a = 0; a < Q_DIM; ++a) acc[a] = 0.0f;

  auto STAGE = [&](int j) {
    char* buf = lds + (size_t)(j & 7) * BUFS;
    size_t bb = (size_t)(unsigned)j * BLKB;
    const char* src = Jrow + (bb & ~(size_t)15);      // 16B-aligned window
    GLD(src +        lane * 16, buf,        16);
    GLD(src + 1024 + lane * 16, buf + 1024, 16);
    if (USE_XT)
      GLD(XtB + (size_t)j * 1024 + mg * 128 + lane * 4, buf + 2048, 4);
  };

  auto CONSUME = [&](int j) {
    const char* buf = lds + (size_t)(j & 7) * BUFS;
    int off;
    if (USE_XT) {
      off = *(const unsigned short*)(buf + 2048 + 2 * lane);   // 84*x, staged
    } else {
      const float* p = X_oh + ((size_t)m * L_DIM + j) * Q_DIM;
      int x = 0;
#pragma unroll
      for (int a = 0; a < Q_DIM; ++a) x = (p[a] > 0.5f) ? a : x;
      off = x * 84;
    }
    const float* row = (const float*)(buf + ((j & 3) << 2) + off);
#pragma unroll
    for (int k = 0; k < 10; ++k) {                    // ds_read2_b32 pairs
      acc[2 * k]     += row[2 * k];
      acc[2 * k + 1] += row[2 * k + 1];
    }
    acc[20] += row[20];
  };

  int P = (i < DEPTH) ? i : DEPTH;
  for (int j = 0; j < P; ++j) STAGE(j);
  int jt = i - DEPTH; if (jt < 0) jt = 0;

#pragma unroll 1
  for (int j = 0; j < jt; ++j) {
    STAGE(j + DEPTH);
    if (USE_XT) {
      asm volatile("s_waitcnt vmcnt(18)" ::: "memory");  // 3*DEPTH newer loads ok
    } else {
      asm volatile("s_waitcnt vmcnt(0)" ::: "memory");   // fallback: X_oh loads pollute count
    }
    __builtin_amdgcn_sched_barrier(0);
    CONSUME(j);
  }
  asm volatile("s_waitcnt vmcnt(0)" ::: "memory");
  __builtin_amdgcn_sched_barrier(0);
#pragma unroll 1
  for (int j = jt; j < i; ++j) CONSUME(j);

  const float* hp = h + i * Q_DIM;
  float* o = out + ((size_t)m * L_DIM + i) * Q_DIM;
#pragma unroll
  for (int a = 0; a < Q_DIM; ++a) o[a] = acc[a] + hp[a];
}

extern "C" void kernel_launch(void* const* d_in, const int* in_sizes, int n_in,
                              void* d_out, int out_size, void* d_ws, size_t ws_size,
                              hipStream_t stream) {
  const float* X_oh = (const float*)d_in[0];
  const float* h    = (const float*)d_in[1];
  const float* Jm   = (const float*)d_in[2];
  float* out        = (float*)d_out;
  unsigned short* Xt = (unsigned short*)d_ws;          // 262144 B

  if (ws_size >= (size_t)M_DIM * L_DIM * sizeof(unsigned short)) {
    ardca_prep<<<2048, 64, 0, stream>>>(X_oh, Xt);
    ardca_main<1><<<2048, 64, 0, stream>>>(Jm, h, Xt, X_oh, out);
  } else {
    ardca_main<0><<<2048, 64, 0, stream>>>(Jm, h, Xt, X_oh, out);
  }
}